// Round 1
// baseline (107.461 us; speedup 1.0000x reference)
//
#include <hip/hip_runtime.h>
#include <hip/hip_bf16.h>

#define NB 16
#define NP 1024
#define NS 32
#define NC 76
#define HSTR 136   // bf16 stride of LDS rows (k dim), 272B = 68 words: conflict-free-min for b128 frag reads
#define TPB 4      // tiles per block; tile = 4 (b,p) points = 128 MFMA columns

typedef __attribute__((ext_vector_type(8))) short bf16x8;
typedef __attribute__((ext_vector_type(4))) short bf16x4;
typedef __attribute__((ext_vector_type(2))) short bf16x2;
typedef __attribute__((ext_vector_type(4))) float f32x4;

__device__ inline short f2bf(float f) {
  unsigned u = __builtin_bit_cast(unsigned, f);
  u = u + 0x7fffu + ((u >> 16) & 1u);   // round-to-nearest-even
  return (short)(u >> 16);
}

// ---------------- kernel 1: per-(b,p) frames ----------------
__global__ void frames_kernel(const float* __restrict__ inp,
                              const float* __restrict__ normal,
                              float* __restrict__ out, float* __restrict__ ws) {
  const int bp = blockIdx.x * 256 + threadIdx.x;   // 0..16383
  const int b = bp >> 10, p = bp & 1023;

  float azi[3];
#pragma unroll
  for (int i = 0; i < 3; ++i) {
    const float* row = inp + (size_t)((b*NC + 6 + i)*NP + p) * NS;
    float s = 0.f;
#pragma unroll
    for (int q = 0; q < 8; ++q) {
      float4 v = ((const float4*)row)[q];
      s += (v.x + v.y) + (v.z + v.w);
    }
    s -= row[0];                  // mean over s=1..31
    azi[i] = s / 31.f;
  }
  float nr[3];
#pragma unroll
  for (int i = 0; i < 3; ++i) nr[i] = normal[(size_t)(b*NP + p)*3 + i];
  float nn = sqrtf(nr[0]*nr[0] + nr[1]*nr[1] + nr[2]*nr[2]) + 1e-8f;
  nr[0] /= nn; nr[1] /= nn; nr[2] /= nn;
  float au[3] = {azi[0], azi[1], azi[2]};
  float an = sqrtf(au[0]*au[0] + au[1]*au[1] + au[2]*au[2]) + 1e-8f;
  au[0] /= an; au[1] /= an; au[2] /= an;
  float d = au[0]*nr[0] + au[1]*nr[1] + au[2]*nr[2];
  float xax[3] = {au[0] - d*nr[0], au[1] - d*nr[1], au[2] - d*nr[2]};
  float xn = sqrtf(xax[0]*xax[0] + xax[1]*xax[1] + xax[2]*xax[2]) + 1e-8f;
  xax[0] /= xn; xax[1] /= xn; xax[2] /= xn;
  float yax[3] = {nr[1]*xax[2] - nr[2]*xax[1],
                  nr[2]*xax[0] - nr[0]*xax[2],
                  nr[0]*xax[1] - nr[1]*xax[0]};
#pragma unroll
  for (int i = 0; i < 3; ++i)
    out[(size_t)(b*131 + i)*NP + p] = au[i];      // azi_u -> out channels 0..2

  float* w = ws + (size_t)bp * 12;                // R rows (xax,yax,n) + R*azi_u
  w[0]=xax[0]; w[1]=xax[1]; w[2]=xax[2];
  w[3]=yax[0]; w[4]=yax[1]; w[5]=yax[2];
  w[6]=nr[0];  w[7]=nr[1];  w[8]=nr[2];
  w[9]  = xax[0]*au[0] + xax[1]*au[1] + xax[2]*au[2];
  w[10] = yax[0]*au[0] + yax[1]*au[1] + yax[2]*au[2];
  w[11] = nr[0]*au[0]  + nr[1]*au[1]  + nr[2]*au[2];
}

// ---------------- kernel 2: fused MLP + pool ----------------
// x layout in LDS (per tile, col-major [col][k], k-stride HSTR):
//   k 0..63  = feats (input ch 12..75)
//   k 64..66 = align(rel), 67..69 = align(other_normal), 70..72 = dir_dif
//   k 73..95 = zero-padded (w1 fragments also zero there)
// w1 column permutation folded into the register fragment load.
__global__ __launch_bounds__(256, 2)
void mlp_kernel(const float* __restrict__ inp, const float* __restrict__ w1g,
                const float* __restrict__ b1g, const float* __restrict__ w2g,
                const float* __restrict__ b2g, const float* __restrict__ ws,
                float* __restrict__ out) {
  __shared__ short xh[128 * HSTR];   // 34.8 KB union buffer: x tile, then h1 tile
  const int tid = threadIdx.x;
  const int lane = tid & 63;
  const int wv = tid >> 6;          // wave 0..3 -> output-row stripe 32*wv
  const int l15 = lane & 15;
  const int l4 = lane >> 4;         // 0..3

  // ----- per-wave weight fragments in registers (loaded once) -----
  bf16x8 w1f[2][3];
#pragma unroll
  for (int mf = 0; mf < 2; ++mf)
#pragma unroll
    for (int ks = 0; ks < 3; ++ks) {
      bf16x8 a;
#pragma unroll
      for (int j = 0; j < 8; ++j) {
        int row = 32*wv + 16*mf + l15;
        int kk = 32*ks + 8*l4 + j;
        float v = 0.f;
        if (kk < 73) {
          int c = (kk < 64) ? (kk + 3) : ((kk < 67) ? (kk - 64) : kk);
          v = w1g[row*73 + c];
        }
        a[j] = f2bf(v);
      }
      w1f[mf][ks] = a;
    }
  bf16x8 w2f[2][4];
#pragma unroll
  for (int mf = 0; mf < 2; ++mf)
#pragma unroll
    for (int ks = 0; ks < 4; ++ks) {
      bf16x8 a;
#pragma unroll
      for (int j = 0; j < 8; ++j) {
        int row = 32*wv + 16*mf + l15;
        int kk = 32*ks + 8*l4 + j;
        a[j] = f2bf(w2g[row*128 + kk]);
      }
      w2f[mf][ks] = a;
    }
  float bias1[2][4], bias2[2][4];
#pragma unroll
  for (int mf = 0; mf < 2; ++mf)
#pragma unroll
    for (int r = 0; r < 4; ++r) {
      int row = 32*wv + 16*mf + 4*l4 + r;
      bias1[mf][r] = b1g[row];
      bias2[mf][r] = b2g[row];
    }

  // zero LDS once: guards against 0*NaN in the padded K region on the first tile
  {
    int* z = (int*)xh;
    for (int i = tid; i < 128*HSTR/2; i += 256) z[i] = 0;
  }
  __syncthreads();

  for (int it = 0; it < TPB; ++it) {
    const int tile = blockIdx.x * TPB + it;       // 0..4095
    const int b = tile >> 8;
    const int pbase = (tile & 255) * 4;

    // ----- fill x tile: feats (k=0..63) -----
    {
      const int s = tid & 31, g = tid >> 5;
#pragma unroll
      for (int lp = 0; lp < 4; ++lp) {
        const int p = pbase + lp;
        const int col = lp*32 + s;
#pragma unroll
        for (int half = 0; half < 2; ++half) {
          const int f0 = 4*g + 32*half;
          bf16x4 pk;
#pragma unroll
          for (int q = 0; q < 4; ++q) {
            float v = inp[(size_t)((b*NC + 12 + f0 + q)*NP + p)*NS + s];
            pk[q] = f2bf(v);
          }
          *(bf16x4*)&xh[col*HSTR + f0] = pk;
        }
      }
    }
    // ----- fill x tile: aligned rows (k=64..72) -----
    if (tid < 128) {
      const int col = tid;
      const int lp = col >> 5, s = col & 31;
      const int p = pbase + lp;
      const float* Rp = ws + (size_t)(b*NP + p)*12;
      float R[12];
#pragma unroll
      for (int i = 0; i < 12; ++i) R[i] = Rp[i];
      float rel[3], on[3], od[3];
#pragma unroll
      for (int i = 0; i < 3; ++i) {
        rel[i] = inp[(size_t)((b*NC + 6 + i)*NP + p)*NS + s];
        on[i]  = inp[(size_t)((b*NC + 3 + i)*NP + p)*NS + s];
        od[i]  = inp[(size_t)((b*NC + 9 + i)*NP + p)*NS + s];
      }
      float xv[9];
#pragma unroll
      for (int r = 0; r < 3; ++r) {
        xv[r]   = R[3*r]*rel[0] + R[3*r+1]*rel[1] + R[3*r+2]*rel[2];
        xv[3+r] = R[3*r]*on[0]  + R[3*r+1]*on[1]  + R[3*r+2]*on[2];
        xv[6+r] = R[9+r] - (R[3*r]*od[0] + R[3*r+1]*od[1] + R[3*r+2]*od[2]);
      }
#pragma unroll
      for (int q = 0; q < 4; ++q) {
        bf16x2 pk2; pk2[0] = f2bf(xv[2*q]); pk2[1] = f2bf(xv[2*q+1]);
        *(bf16x2*)&xh[col*HSTR + 64 + 2*q] = pk2;
      }
      xh[col*HSTR + 72] = f2bf(xv[8]);
    }
    __syncthreads();

    // ----- layer 1: h1 = relu(w1 @ x + b1), K=96 (padded) -----
    f32x4 acc1[2][8];
#pragma unroll
    for (int mf = 0; mf < 2; ++mf)
#pragma unroll
      for (int nf = 0; nf < 8; ++nf) acc1[mf][nf] = f32x4{0.f,0.f,0.f,0.f};
#pragma unroll
    for (int ks = 0; ks < 3; ++ks) {
      bf16x8 bv[8];
#pragma unroll
      for (int nf = 0; nf < 8; ++nf)
        bv[nf] = *(const bf16x8*)&xh[(16*nf + l15)*HSTR + 32*ks + 8*l4];
#pragma unroll
      for (int mf = 0; mf < 2; ++mf)
#pragma unroll
        for (int nf = 0; nf < 8; ++nf)
          acc1[mf][nf] = __builtin_amdgcn_mfma_f32_16x16x32_bf16(
              w1f[mf][ks], bv[nf], acc1[mf][nf], 0, 0, 0);
    }
    __syncthreads();   // all L1 reads done before h1 overwrites xh

    // store h1 col-major [col][k=row] for layer-2 B fragments
#pragma unroll
    for (int mf = 0; mf < 2; ++mf)
#pragma unroll
      for (int nf = 0; nf < 8; ++nf) {
        const int col = 16*nf + l15;
        const int row0 = 32*wv + 16*mf + 4*l4;
        bf16x4 pk;
#pragma unroll
        for (int r = 0; r < 4; ++r)
          pk[r] = f2bf(fmaxf(acc1[mf][nf][r] + bias1[mf][r], 0.f));
        *(bf16x4*)&xh[col*HSTR + row0] = pk;
      }
    __syncthreads();

    // ----- layer 2: h2 = relu(w2 @ h1 + b2), K=128 -----
    f32x4 acc2[2][8];
#pragma unroll
    for (int mf = 0; mf < 2; ++mf)
#pragma unroll
      for (int nf = 0; nf < 8; ++nf) acc2[mf][nf] = f32x4{0.f,0.f,0.f,0.f};
#pragma unroll
    for (int ks = 0; ks < 4; ++ks) {
      bf16x8 bv[8];
#pragma unroll
      for (int nf = 0; nf < 8; ++nf)
        bv[nf] = *(const bf16x8*)&xh[(16*nf + l15)*HSTR + 32*ks + 8*l4];
#pragma unroll
      for (int mf = 0; mf < 2; ++mf)
#pragma unroll
        for (int nf = 0; nf < 8; ++nf)
          acc2[mf][nf] = __builtin_amdgcn_mfma_f32_16x16x32_bf16(
              w2f[mf][ks], bv[nf], acc2[mf][nf], 0, 0, 0);
    }

    // ----- relu + max-pool over s (16-lane shuffle reduce) + store -----
#pragma unroll
    for (int mf = 0; mf < 2; ++mf)
#pragma unroll
      for (int r = 0; r < 4; ++r)
#pragma unroll
        for (int lp = 0; lp < 4; ++lp) {
          float v = fmaxf(fmaxf(acc2[mf][2*lp][r], acc2[mf][2*lp+1][r]) + bias2[mf][r], 0.f);
#pragma unroll
          for (int off = 1; off < 16; off <<= 1)
            v = fmaxf(v, __shfl_xor(v, off));
          if (l15 == lp) {
            const int row = 32*wv + 16*mf + 4*l4 + r;
            out[(size_t)(b*131 + 3 + row)*NP + pbase + lp] = v;
          }
        }
    __syncthreads();   // xh reads complete before next tile's fill
  }
}

extern "C" void kernel_launch(void* const* d_in, const int* in_sizes, int n_in,
                              void* d_out, int out_size, void* d_ws, size_t ws_size,
                              hipStream_t stream) {
  const float* inp    = (const float*)d_in[0];
  const float* normal = (const float*)d_in[1];
  const float* w1     = (const float*)d_in[2];
  const float* b1     = (const float*)d_in[3];
  const float* w2     = (const float*)d_in[4];
  const float* b2     = (const float*)d_in[5];
  float* out = (float*)d_out;
  float* ws  = (float*)d_ws;    // needs 16384*12*4 = 786,432 B

  frames_kernel<<<dim3((NB*NP)/256), dim3(256), 0, stream>>>(inp, normal, out, ws);
  mlp_kernel<<<dim3((NB*NP/4)/TPB), dim3(256), 0, stream>>>(inp, w1, b1, w2, b2, ws, out);
}